// Round 1
// baseline (194.004 us; speedup 1.0000x reference)
//
#include <hip/hip_runtime.h>
#include <hip/hip_bf16.h>

// Problem constants (fixed shapes): B=2, F=32, C=4, D=64, H=128, W=128
#define S_VOX  1048576          // D*H*W = 2^20
#define NVOX   2097152          // B * S_VOX
#define NCLS   4
#define NFEAT  32
#define FEAT_ELEMS 67108864     // B*F*S_VOX
#define EPS_F  1e-8f
#define LOG2_F 0.6931471805599453f

// ---- monotonic float <-> orderable uint key ----
__device__ __forceinline__ unsigned f2key(float f) {
    unsigned u = __float_as_uint(f);
    return (u & 0x80000000u) ? ~u : (u | 0x80000000u);
}
__device__ __forceinline__ float key2f(unsigned k) {
    unsigned u = (k & 0x80000000u) ? (k & 0x7FFFFFFFu) : ~k;
    return __uint_as_float(u);
}

// ws layout (bytes):
//   0   : unsigned mink[4]
//   16  : unsigned maxk[4]
//   32  : int      i64flag
//   64  : float    params[8]   (base[4], mult[4])
//   256 : float    dis[NVOX]

// Init atomic slots + detect whether pseudo_labels is int64 (odd 32-bit words
// of the first 128 all zero while some even word nonzero) or int32.
__global__ void k_prolog(const unsigned* __restrict__ lab32,
                         unsigned* __restrict__ mink, unsigned* __restrict__ maxk,
                         int* __restrict__ flag) {
    int t = threadIdx.x;            // 64 threads
    if (t < NCLS) { mink[t] = 0xFFFFFFFFu; maxk[t] = 0u; }
    unsigned even = lab32[2 * t];
    unsigned odd  = lab32[2 * t + 1];
    unsigned long long oddnz  = __ballot(odd  != 0u);
    unsigned long long evennz = __ballot(even != 0u);
    if (t == 0) *flag = (oddnz == 0ull && evennz != 0ull) ? 1 : 0;
}

__global__ void __launch_bounds__(256)
k_dis(const float* __restrict__ lA, const float* __restrict__ lB,
      const unsigned* __restrict__ lab32, const int* __restrict__ i64flag,
      float* __restrict__ dis,
      unsigned* __restrict__ mink, unsigned* __restrict__ maxk) {
    __shared__ unsigned smin[NCLS], smax[NCLS];
    if (threadIdx.x < NCLS) { smin[threadIdx.x] = 0xFFFFFFFFu; smax[threadIdx.x] = 0u; }
    __syncthreads();

    const int lstride = 1 + *i64flag;   // 1 if int32, 2 if int64 (low word)
    unsigned lmin[NCLS] = {0xFFFFFFFFu, 0xFFFFFFFFu, 0xFFFFFFFFu, 0xFFFFFFFFu};
    unsigned lmax[NCLS] = {0u, 0u, 0u, 0u};

    const int nquad = NVOX / 4;
    for (int q = blockIdx.x * blockDim.x + threadIdx.x; q < nquad;
         q += gridDim.x * blockDim.x) {
        const int g = q << 2;                 // base voxel index
        const int b = g >> 20;                // batch
        const int v = g & (S_VOX - 1);
        const size_t abase = ((size_t)b * NCLS) * S_VOX + v;

        float4 a0 = *(const float4*)(lA + abase);
        float4 a1 = *(const float4*)(lA + abase + S_VOX);
        float4 a2 = *(const float4*)(lA + abase + 2 * (size_t)S_VOX);
        float4 a3 = *(const float4*)(lA + abase + 3 * (size_t)S_VOX);
        float4 c0 = *(const float4*)(lB + abase);
        float4 c1 = *(const float4*)(lB + abase + S_VOX);
        float4 c2 = *(const float4*)(lB + abase + 2 * (size_t)S_VOX);
        float4 c3 = *(const float4*)(lB + abase + 3 * (size_t)S_VOX);

        float dv[4];
        #pragma unroll
        for (int j = 0; j < 4; ++j) {
            float av[NCLS] = { ((const float*)&a0)[j], ((const float*)&a1)[j],
                               ((const float*)&a2)[j], ((const float*)&a3)[j] };
            float bv[NCLS] = { ((const float*)&c0)[j], ((const float*)&c1)[j],
                               ((const float*)&c2)[j], ((const float*)&c3)[j] };
            float maxA = fmaxf(fmaxf(av[0], av[1]), fmaxf(av[2], av[3]));
            float maxB = fmaxf(fmaxf(bv[0], bv[1]), fmaxf(bv[2], bv[3]));
            float eA[NCLS], eB[NCLS];
            float sA = 0.f, sB = 0.f;
            #pragma unroll
            for (int c = 0; c < NCLS; ++c) {
                eA[c] = __expf(av[c] - maxA); sA += eA[c];
                eB[c] = __expf(bv[c] - maxB); sB += eB[c];
            }
            float lseA = __logf(sA), lseB = __logf(sB);
            float rsA = 1.f / sA, rsB = 1.f / sB;
            float kl = 0.f;
            #pragma unroll
            for (int c = 0; c < NCLS; ++c) {
                float pA  = eA[c] * rsA;
                float pB  = eB[c] * rsB;
                float la  = av[c] - maxA - lseA;   // log pA
                float lb  = bv[c] - maxB - lseB;   // log pB
                float lM  = __logf(0.5f * (pA + pB) + EPS_F);
                kl += pA * (la - lM) + pB * (lb - lM);
            }
            dv[j] = 0.5f * kl;
        }

        *(float4*)(dis + g) = make_float4(dv[0], dv[1], dv[2], dv[3]);

        #pragma unroll
        for (int j = 0; j < 4; ++j) {
            int lbl = (int)lab32[(size_t)(g + j) * lstride];
            unsigned key = f2key(dv[j]);
            #pragma unroll
            for (int c = 0; c < NCLS; ++c) {
                if (lbl == c) {
                    lmin[c] = min(lmin[c], key);
                    lmax[c] = max(lmax[c], key);
                }
            }
        }
    }

    // wave reduce (64 lanes)
    #pragma unroll
    for (int off = 32; off > 0; off >>= 1) {
        #pragma unroll
        for (int c = 0; c < NCLS; ++c) {
            unsigned om = (unsigned)__shfl_xor((int)lmin[c], off);
            unsigned oM = (unsigned)__shfl_xor((int)lmax[c], off);
            lmin[c] = min(lmin[c], om);
            lmax[c] = max(lmax[c], oM);
        }
    }
    if ((threadIdx.x & 63) == 0) {
        #pragma unroll
        for (int c = 0; c < NCLS; ++c) {
            atomicMin(&smin[c], lmin[c]);
            atomicMax(&smax[c], lmax[c]);
        }
    }
    __syncthreads();
    if (threadIdx.x < NCLS) {
        atomicMin(&mink[threadIdx.x], smin[threadIdx.x]);
        atomicMax(&maxk[threadIdx.x], smax[threadIdx.x]);
    }
}

// Fold per-class stats into gamma = base[c] + mult[c] * dis
__global__ void k_stats(const unsigned* __restrict__ mink, const unsigned* __restrict__ maxk,
                        const float* __restrict__ ranks, float* __restrict__ params) {
    int c = threadIdx.x;
    if (c >= NCLS) return;
    unsigned kmin = mink[c], kmax = maxk[c];
    bool present = (kmin != 0xFFFFFFFFu);
    float dmin = present ? key2f(kmin) : 0.0f;
    float dmax = present ? key2f(kmax) : LOG2_F;
    float inter = 1.0f - ranks[c] * (1.0f / (NCLS - 1));
    float base, mult;
    if (dmax > dmin) {
        float inv = 1.0f / (dmax - dmin + EPS_F);
        mult = inter * inv;
        base = 1.0f - mult * dmin;
    } else {
        mult = 0.0f;
        base = 1.0f + 0.5f * inter;
    }
    params[c] = base;
    params[NCLS + c] = mult;
}

__global__ void __launch_bounds__(256)
k_apply(const float* __restrict__ feat, const unsigned* __restrict__ lab32,
        const int* __restrict__ i64flag, const float* __restrict__ dis,
        const float* __restrict__ params, float* __restrict__ out) {
    const int q = blockIdx.x * blockDim.x + threadIdx.x;
    const int g = q << 2;
    if (g >= NVOX) return;
    const int lstride = 1 + *i64flag;

    float4 d4 = *(const float4*)(dis + g);
    float ga[4];
    #pragma unroll
    for (int j = 0; j < 4; ++j) {
        int lbl = (int)lab32[(size_t)(g + j) * lstride];
        ga[j] = params[lbl] + params[NCLS + lbl] * ((const float*)&d4)[j];
    }

    // gamma_map output (after the scaled features)
    *(float4*)(out + (size_t)FEAT_ELEMS + g) = make_float4(ga[0], ga[1], ga[2], ga[3]);

    const int b = g >> 20;
    const int v = g & (S_VOX - 1);
    const size_t fbase = ((size_t)b * NFEAT) * S_VOX + v;
    #pragma unroll 8
    for (int f = 0; f < NFEAT; ++f) {
        const size_t off = fbase + (size_t)f * S_VOX;
        float4 x = *(const float4*)(feat + off);
        x.x *= ga[0]; x.y *= ga[1]; x.z *= ga[2]; x.w *= ga[3];
        *(float4*)(out + off) = x;
    }
}

extern "C" void kernel_launch(void* const* d_in, const int* in_sizes, int n_in,
                              void* d_out, int out_size, void* d_ws, size_t ws_size,
                              hipStream_t stream) {
    const float*    feat  = (const float*)d_in[0];
    const float*    lA    = (const float*)d_in[1];
    const float*    lB    = (const float*)d_in[2];
    const unsigned* lab32 = (const unsigned*)d_in[3];
    const float*    ranks = (const float*)d_in[4];
    float* out = (float*)d_out;

    char* ws = (char*)d_ws;
    unsigned* mink  = (unsigned*)(ws + 0);
    unsigned* maxk  = (unsigned*)(ws + 16);
    int*      flag  = (int*)(ws + 32);
    float*    params = (float*)(ws + 64);
    float*    dis   = (float*)(ws + 256);

    k_prolog<<<1, 64, 0, stream>>>(lab32, mink, maxk, flag);
    k_dis<<<1024, 256, 0, stream>>>(lA, lB, lab32, flag, dis, mink, maxk);
    k_stats<<<1, 64, 0, stream>>>(mink, maxk, ranks, params);
    k_apply<<<NVOX / 4 / 256, 256, 0, stream>>>(feat, lab32, flag, dis, params, out);
}

// Round 3
// 148.208 us; speedup vs baseline: 1.3090x; 1.3090x over previous
//
#include <hip/hip_runtime.h>
#include <hip/hip_bf16.h>

// Problem constants (fixed shapes): B=2, F=32, C=4, D=64, H=128, W=128
#define S_VOX  1048576          // D*H*W = 2^20
#define NVOX   2097152          // B * S_VOX
#define NCLS   4
#define NFEAT  32
#define FEAT_ELEMS 67108864     // B*F*S_VOX
#define EPS_F  1e-8f
#define LOG2_F 0.6931471805599453f

typedef float f32x4 __attribute__((ext_vector_type(4)));

// ---- monotonic float <-> orderable uint key ----
__device__ __forceinline__ unsigned f2key(float f) {
    unsigned u = __float_as_uint(f);
    return (u & 0x80000000u) ? ~u : (u | 0x80000000u);
}
__device__ __forceinline__ float key2f(unsigned k) {
    unsigned u = (k & 0x80000000u) ? (k & 0x7FFFFFFFu) : ~k;
    return __uint_as_float(u);
}

// ws layout (bytes):
//   0   : unsigned mink[4]
//   16  : unsigned maxk[4]
//   32  : int      i64flag
//   64  : float    params[8]   (base[4], mult[4])
//   256 : float    dis[NVOX]

__global__ void k_prolog(const unsigned* __restrict__ lab32,
                         unsigned* __restrict__ mink, unsigned* __restrict__ maxk,
                         int* __restrict__ flag) {
    int t = threadIdx.x;            // 64 threads
    if (t < NCLS) { mink[t] = 0xFFFFFFFFu; maxk[t] = 0u; }
    unsigned even = lab32[2 * t];
    unsigned odd  = lab32[2 * t + 1];
    unsigned long long oddnz  = __ballot(odd  != 0u);
    unsigned long long evennz = __ballot(even != 0u);
    if (t == 0) *flag = (oddnz == 0ull && evennz != 0ull) ? 1 : 0;
}

__global__ void __launch_bounds__(256)
k_dis(const float* __restrict__ lA, const float* __restrict__ lB,
      const unsigned* __restrict__ lab32, const int* __restrict__ i64flag,
      float* __restrict__ dis,
      unsigned* __restrict__ mink, unsigned* __restrict__ maxk) {
    __shared__ unsigned smin[NCLS], smax[NCLS];
    if (threadIdx.x < NCLS) { smin[threadIdx.x] = 0xFFFFFFFFu; smax[threadIdx.x] = 0u; }
    __syncthreads();

    const int lstride = 1 + *i64flag;   // 1 if int32, 2 if int64 (low word)
    unsigned lmin[NCLS] = {0xFFFFFFFFu, 0xFFFFFFFFu, 0xFFFFFFFFu, 0xFFFFFFFFu};
    unsigned lmax[NCLS] = {0u, 0u, 0u, 0u};

    const int nquad = NVOX / 4;
    for (int q = blockIdx.x * blockDim.x + threadIdx.x; q < nquad;
         q += gridDim.x * blockDim.x) {
        const int g = q << 2;                 // base voxel index
        const int b = g >> 20;                // batch
        const int v = g & (S_VOX - 1);
        const size_t abase = ((size_t)b * NCLS) * S_VOX + v;

        float4 a0 = *(const float4*)(lA + abase);
        float4 a1 = *(const float4*)(lA + abase + S_VOX);
        float4 a2 = *(const float4*)(lA + abase + 2 * (size_t)S_VOX);
        float4 a3 = *(const float4*)(lA + abase + 3 * (size_t)S_VOX);
        float4 c0 = *(const float4*)(lB + abase);
        float4 c1 = *(const float4*)(lB + abase + S_VOX);
        float4 c2 = *(const float4*)(lB + abase + 2 * (size_t)S_VOX);
        float4 c3 = *(const float4*)(lB + abase + 3 * (size_t)S_VOX);

        float dv[4];
        #pragma unroll
        for (int j = 0; j < 4; ++j) {
            float av[NCLS] = { ((const float*)&a0)[j], ((const float*)&a1)[j],
                               ((const float*)&a2)[j], ((const float*)&a3)[j] };
            float bv[NCLS] = { ((const float*)&c0)[j], ((const float*)&c1)[j],
                               ((const float*)&c2)[j], ((const float*)&c3)[j] };
            float maxA = fmaxf(fmaxf(av[0], av[1]), fmaxf(av[2], av[3]));
            float maxB = fmaxf(fmaxf(bv[0], bv[1]), fmaxf(bv[2], bv[3]));
            float eA[NCLS], eB[NCLS];
            float sA = 0.f, sB = 0.f;
            #pragma unroll
            for (int c = 0; c < NCLS; ++c) {
                eA[c] = __expf(av[c] - maxA); sA += eA[c];
                eB[c] = __expf(bv[c] - maxB); sB += eB[c];
            }
            float lseA = __logf(sA), lseB = __logf(sB);
            float rsA = 1.f / sA, rsB = 1.f / sB;
            float kl = 0.f;
            #pragma unroll
            for (int c = 0; c < NCLS; ++c) {
                float pA  = eA[c] * rsA;
                float pB  = eB[c] * rsB;
                float la  = av[c] - maxA - lseA;   // log pA
                float lb  = bv[c] - maxB - lseB;   // log pB
                float lM  = __logf(0.5f * (pA + pB) + EPS_F);
                kl += pA * (la - lM) + pB * (lb - lM);
            }
            dv[j] = 0.5f * kl;
        }

        *(float4*)(dis + g) = make_float4(dv[0], dv[1], dv[2], dv[3]);

        #pragma unroll
        for (int j = 0; j < 4; ++j) {
            int lbl = (int)lab32[(size_t)(g + j) * lstride];
            unsigned key = f2key(dv[j]);
            #pragma unroll
            for (int c = 0; c < NCLS; ++c) {
                if (lbl == c) {
                    lmin[c] = min(lmin[c], key);
                    lmax[c] = max(lmax[c], key);
                }
            }
        }
    }

    // wave reduce (64 lanes)
    #pragma unroll
    for (int off = 32; off > 0; off >>= 1) {
        #pragma unroll
        for (int c = 0; c < NCLS; ++c) {
            unsigned om = (unsigned)__shfl_xor((int)lmin[c], off);
            unsigned oM = (unsigned)__shfl_xor((int)lmax[c], off);
            lmin[c] = min(lmin[c], om);
            lmax[c] = max(lmax[c], oM);
        }
    }
    if ((threadIdx.x & 63) == 0) {
        #pragma unroll
        for (int c = 0; c < NCLS; ++c) {
            atomicMin(&smin[c], lmin[c]);
            atomicMax(&smax[c], lmax[c]);
        }
    }
    __syncthreads();
    if (threadIdx.x < NCLS) {
        atomicMin(&mink[threadIdx.x], smin[threadIdx.x]);
        atomicMax(&maxk[threadIdx.x], smax[threadIdx.x]);
    }
}

// Fold per-class stats into gamma = base[c] + mult[c] * dis
__global__ void k_stats(const unsigned* __restrict__ mink, const unsigned* __restrict__ maxk,
                        const float* __restrict__ ranks, float* __restrict__ params) {
    int c = threadIdx.x;
    if (c >= NCLS) return;
    unsigned kmin = mink[c], kmax = maxk[c];
    bool present = (kmin != 0xFFFFFFFFu);
    float dmin = present ? key2f(kmin) : 0.0f;
    float dmax = present ? key2f(kmax) : LOG2_F;
    float inter = 1.0f - ranks[c] * (1.0f / (NCLS - 1));
    float base, mult;
    if (dmax > dmin) {
        float inv = 1.0f / (dmax - dmin + EPS_F);
        mult = inter * inv;
        base = 1.0f - mult * dmin;
    } else {
        mult = 0.0f;
        base = 1.0f + 0.5f * inter;
    }
    params[c] = base;
    params[NCLS + c] = mult;
}

// gamma_map = base[lbl] + mult[lbl]*dis  -> written at out + FEAT_ELEMS
__global__ void __launch_bounds__(256)
k_gamma(const unsigned* __restrict__ lab32, const int* __restrict__ i64flag,
        const float* __restrict__ dis, const float* __restrict__ params,
        float* __restrict__ gamma_out) {
    const int q = blockIdx.x * blockDim.x + threadIdx.x;
    const int g = q << 2;
    if (g >= NVOX) return;
    const int lstride = 1 + *i64flag;

    float4 d4 = *(const float4*)(dis + g);
    float ga[4];
    #pragma unroll
    for (int j = 0; j < 4; ++j) {
        int lbl = (int)lab32[(size_t)(g + j) * lstride];
        ga[j] = params[lbl] + params[NCLS + lbl] * ((const float*)&d4)[j];
    }
    *(float4*)(gamma_out + g) = make_float4(ga[0], ga[1], ga[2], ga[3]);
}

// Pure streaming scale: out[e] = feat[e] * gamma[b*S_VOX + v], linear walk.
__global__ void __launch_bounds__(256)
k_scale(const float* __restrict__ feat, const float* __restrict__ gamma,
        float* __restrict__ out) {
    const size_t nquad = FEAT_ELEMS / 4;          // 16M float4s
    const size_t stride = (size_t)gridDim.x * blockDim.x;
    for (size_t i = (size_t)blockIdx.x * blockDim.x + threadIdx.x; i < nquad;
         i += stride) {
        const size_t e = i << 2;                  // element index
        const int b = (int)(e >> 25);             // e / (NFEAT*S_VOX)
        const int v = (int)(e & (S_VOX - 1));
        // feature stream: non-temporal (no reuse); gamma: cached (32x reuse)
        f32x4 x = __builtin_nontemporal_load((const f32x4*)(feat + e));
        f32x4 gmm = *(const f32x4*)(gamma + ((size_t)b << 20) + v);
        x *= gmm;
        __builtin_nontemporal_store(x, (f32x4*)(out + e));
    }
}

extern "C" void kernel_launch(void* const* d_in, const int* in_sizes, int n_in,
                              void* d_out, int out_size, void* d_ws, size_t ws_size,
                              hipStream_t stream) {
    const float*    feat  = (const float*)d_in[0];
    const float*    lA    = (const float*)d_in[1];
    const float*    lB    = (const float*)d_in[2];
    const unsigned* lab32 = (const unsigned*)d_in[3];
    const float*    ranks = (const float*)d_in[4];
    float* out = (float*)d_out;

    char* ws = (char*)d_ws;
    unsigned* mink   = (unsigned*)(ws + 0);
    unsigned* maxk   = (unsigned*)(ws + 16);
    int*      flag   = (int*)(ws + 32);
    float*    params = (float*)(ws + 64);
    float*    dis    = (float*)(ws + 256);

    float* gamma_out = out + (size_t)FEAT_ELEMS;

    k_prolog<<<1, 64, 0, stream>>>(lab32, mink, maxk, flag);
    k_dis<<<1024, 256, 0, stream>>>(lA, lB, lab32, flag, dis, mink, maxk);
    k_stats<<<1, 64, 0, stream>>>(mink, maxk, ranks, params);
    k_gamma<<<NVOX / 4 / 256, 256, 0, stream>>>(lab32, flag, dis, params, gamma_out);
    k_scale<<<8192, 256, 0, stream>>>(feat, gamma_out, out);
}